// Round 6
// baseline (675.060 us; speedup 1.0000x reference)
//
#include <hip/hip_runtime.h>
#include <math.h>

#define BOX 128
#define MCELLS (BOX*BOX*BOX)
#define TABN 512
#define SATN 256
typedef unsigned short u16;

__device__ __forceinline__ float bf2f(u16 h) {
  union { unsigned u; float f; } c; c.u = ((unsigned)h) << 16; return c.f;
}
__device__ __forceinline__ u16 f2bf(float f) {
  union { float f; unsigned u; } c; c.f = f;
  unsigned r = c.u + 0x7FFF + ((c.u >> 16) & 1);   // RNE
  return (u16)(r >> 16);
}
__device__ __forceinline__ unsigned pk2(float a, float b) {
  return (unsigned)f2bf(a) | ((unsigned)f2bf(b) << 16);
}
__device__ __forceinline__ float plo(unsigned p) {
  union { unsigned u; float f; } c; c.u = p << 16; return c.f;
}
__device__ __forceinline__ float phh(unsigned p) {
  union { unsigned u; float f; } c; c.u = p & 0xFFFF0000u; return c.f;
}
__device__ __forceinline__ void up8(uint4 p, float* o) {
  o[0] = plo(p.x); o[1] = phh(p.x); o[2] = plo(p.y); o[3] = phh(p.y);
  o[4] = plo(p.z); o[5] = phh(p.z); o[6] = plo(p.w); o[7] = phh(p.w);
}
__device__ __forceinline__ uint4 pk8(const float* o) {
  return make_uint4(pk2(o[0], o[1]), pk2(o[2], o[3]),
                    pk2(o[4], o[5]), pk2(o[6], o[7]));
}

// f(u) = log(clip(0.5*(1+erf(u)))) — table builder only
__device__ __forceinline__ float f_exact(float u) {
  float au = fabsf(u);
  float tt = __builtin_amdgcn_rcpf(fmaf(0.3275911f, au, 1.0f));
  float poly = tt * fmaf(tt, fmaf(tt, fmaf(tt, fmaf(tt, 1.061405429f,
                   -1.453152027f), 1.421413741f), -0.284496736f),
                   0.254829592f);
  float e = fmaf(-poly, __expf(-u * u), 1.0f);
  float erfu = (u < 0.0f) ? -e : e;
  float s = fmaf(0.5f, erfu, 0.5f);
  s = fminf(fmaxf(s, 1e-6f), 1.0f);
  return __logf(s);
}

// table over u in [-1.8, 2.2); last bin EXACTLY zero (bulk invariant).
// raw v_sqrt_f32 (<=1 ulp) instead of the IEEE sqrt expansion (~10 instr).
__device__ __forceinline__ float tlookf(const float2* __restrict__ ftab,
                                        float r2, float aoff, float hidu) {
  float r = __builtin_amdgcn_sqrtf(r2);
  float t = fmaf(r, hidu, aoff);
  t = fminf(fmaxf(t, 0.0f), 511.75f);
  int j = (int)t;
  float fr = t - (float)j;
  float2 e = ftab[j];
  return fmaf(fr, e.y, e.x);
}

// ---------------------------------------------------------------------------
// Stage A (gather): one block per 8x8x8 tile, 2 z-cells/thread. Per-atom
// constants (cw2, aW) precomputed at gather time; xy pair-sums hoisted out
// of the k loop; raw v_sqrt in tlookf.
// ---------------------------------------------------------------------------
__global__ __launch_bounds__(256) void eps_gather_kernel(
    const float* __restrict__ coords, const float* __restrict__ params,
    const int* __restrict__ num_atoms, float* __restrict__ eps_out, int N) {
  __shared__ float4 satA[SATN];
  __shared__ float  satW[SATN];
  __shared__ float2 ftab[TABN];
  __shared__ int scnt;

  const int xt = blockIdx.x, yt = blockIdx.y;
  const int bz = blockIdx.z;
  const int b = bz >> 4, zt = bz & 15;
  const int tid = threadIdx.x;

  const float u0 = -1.8f;
  const float du = (2.2f - u0) / (float)TABN;
  const float inv_du = (float)TABN / (2.2f - u0);
  const float hidu = 0.5f * inv_du;
  const float dAI = 0.2f * inv_du;

  if (tid == 0) scnt = 0;
  __syncthreads();

  const float lox = (float)(xt * 8), hix = lox + 7.5f;
  const float loy = (float)(yt * 8), hiy = loy + 7.5f;
  const float loz = (float)(zt * 8), hiz = loz + 7.5f;

  const int na = num_atoms[b];
  for (int a = tid; a < N; a += 256) {
    if (a < na) {
      float ax = coords[(size_t)b * 3 * N + a * 3 + 0];
      float ay = coords[(size_t)b * 3 * N + a * 3 + 1];
      float az = coords[(size_t)b * 3 * N + a * 3 + 2];
      float rad = params[((size_t)b * N + a) * 2 + 1];
      float cx = fminf(fmaxf(ax, lox), hix);
      float cy = fminf(fmaxf(ay, loy), hiy);
      float cz = fminf(fmaxf(az, loz), hiz);
      float ddx = ax - cx, ddy = ay - cy, ddz = az - cz;
      float cut = rad + 5.85f;            // Rw + 4.4 (u<2.2) + slack
      if (ddx * ddx + ddy * ddy + ddz * ddz < cut * cut) {
        int s = atomicAdd(&scnt, 1);
        if (s < SATN) {
          float Rw = rad + 1.4f;
          float cw = rad + 5.8f;          // Rw + 4.4
          satA[s] = make_float4(ax, ay, az, cw * cw);
          satW[s] = (1.8f - 0.5f * Rw) * inv_du;
        }
      }
    }
  }
  __syncthreads();
  const int cnt = min(scnt, SATN);

  const int zq = tid & 3, yy = (tid >> 2) & 7, xx = tid >> 5;
  const int xi = xt * 8 + xx, yi = yt * 8 + yy, zi = zt * 8 + zq * 2;
  const int v = (xi << 14) + (yi << 7) + zi;
  const size_t eb = (size_t)b * 4 * MCELLS;

  if (cnt == 0) {
    *(float2*)(eps_out + eb + 0 * MCELLS + v) = make_float2(79.0f, 79.0f);
    *(float2*)(eps_out + eb + 1 * MCELLS + v) = make_float2(79.0f, 79.0f);
    *(float2*)(eps_out + eb + 2 * MCELLS + v) = make_float2(79.0f, 79.0f);
    *(float2*)(eps_out + eb + (size_t)3 * MCELLS + v) = make_float2(0.0f, 0.0f);
    return;
  }

  for (int j = tid; j < TABN; j += 256) {
    float uj = fmaf(du, (float)j, u0);
    float f0 = f_exact(uj);
    float f1 = f_exact(uj + du);
    ftab[j] = (j == TABN - 1) ? make_float2(0.0f, 0.0f)
                              : make_float2(f0, f1 - f0);
  }
  __syncthreads();

  const float xf = (float)xi, yf = (float)yi, zf = (float)zi;
  float acc[4][2] = {{0.f, 0.f}, {0.f, 0.f}, {0.f, 0.f}, {0.f, 0.f}};

  for (int j = 0; j < cnt; ++j) {
    float4 A = satA[j];
    float aW = satW[j];
    float dx = xf - A.x, dy = yf - A.y, dzb = zf - A.z;
    float cw2 = A.w;

    float dx2 = dx * dx, dxh = dx + 0.5f, dxh2 = dxh * dxh;
    float dy2 = dy * dy, dyh = dy + 0.5f, dyh2 = dyh * dyh;
    float mdx = fminf(dx2, dxh2);
    float mdy = fminf(dy2, dyh2);
    float zhi = dzb + 1.5f;
    float mdz = (dzb > 0.f) ? dzb * dzb : (zhi < 0.f ? zhi * zhi : 0.f);
    if (mdx + mdy + mdz >= cw2) continue;

    float aI = aW + dAI;
    float sW0 = dxh2 + dy2, sW1 = dx2 + dyh2, sxy = dx2 + dy2;
#pragma unroll
    for (int k = 0; k < 2; ++k) {
      float dzv = dzb + (float)k;
      float dz2 = dzv * dzv, dzh = dzv + 0.5f, dzh2 = dzh * dzh;
      acc[0][k] += tlookf(ftab, sW0 + dz2, aW, hidu);
      acc[1][k] += tlookf(ftab, sW1 + dz2, aW, hidu);
      acc[2][k] += tlookf(ftab, sxy + dzh2, aW, hidu);
      acc[3][k] += tlookf(ftab, sxy + dz2, aI, hidu);
    }
  }

#pragma unroll
  for (int ch = 0; ch < 4; ++ch) {
    float e0 = __expf(acc[ch][0]), e1 = __expf(acc[ch][1]);
    float2 o = (ch < 3)
        ? make_float2(fmaf(72.5f, e0, 6.5f), fmaf(72.5f, e1, 6.5f))
        : make_float2(1.0f - e0, 1.0f - e1);
    *(float2*)(eps_out + eb + (size_t)ch * MCELLS + v) = o;
  }
}

// ---------------------------------------------------------------------------
// Stage B: trilinear charge scatter (CHARGE_CONV folded in).
// ---------------------------------------------------------------------------
__global__ __launch_bounds__(256) void q_scatter_kernel(
    const float* __restrict__ coords, const float* __restrict__ params,
    const int* __restrict__ num_atoms, float* __restrict__ q, int N, int B) {
  int t = blockIdx.x * blockDim.x + threadIdx.x;
  if (t >= B * N) return;
  int b = t / N, atom = t % N;
  if (atom >= num_atoms[b]) return;

  const float x = coords[(size_t)b * 3 * N + atom * 3 + 0];
  const float y = coords[(size_t)b * 3 * N + atom * 3 + 1];
  const float z = coords[(size_t)b * 3 * N + atom * 3 + 2];
  const float c = params[((size_t)b * N + atom) * 2 + 0] * 7046.52f;

  float fx0 = floorf(x), fy0 = floorf(y), fz0 = floorf(z);
  int ix = (int)fx0, iy = (int)fy0, iz = (int)fz0;
  float fx = x - fx0, fy = y - fy0, fz = z - fz0;

  float* __restrict__ g = q + (size_t)b * MCELLS;
  for (int k = 0; k < 8; ++k) {
    int cx = (k >> 2) & 1, cy = (k >> 1) & 1, cz = k & 1;
    int jx = ix + cx, jy = iy + cy, jz = iz + cz;
    if ((unsigned)jx >= (unsigned)BOX || (unsigned)jy >= (unsigned)BOX ||
        (unsigned)jz >= (unsigned)BOX) continue;
    float w = (cx ? fx : 1.0f - fx) * (cy ? fy : 1.0f - fy) *
              (cz ? fz : 1.0f - fz);
    atomicAdd(&g[(jx * BOX + jy) * BOX + jz], w * c);
  }
}

// ---------------------------------------------------------------------------
// Prep (8 cells/thread): reads fp32 eps + q (coalesced); writes bf16 packs
// ex/ey/ez/rd/rq, phiA = rq (sweep 1), and per-column 16-bit purity MASKS
// (bit zg = z-octet zg of the column is pure).
// ---------------------------------------------------------------------------
__global__ __launch_bounds__(256) void prep8_kernel(
    const float* __restrict__ eps, const float* __restrict__ q,
    u16* __restrict__ exb, u16* __restrict__ eyb, u16* __restrict__ ezb,
    u16* __restrict__ rdn, u16* __restrict__ rq2, u16* __restrict__ phiA,
    u16* __restrict__ pure16, int B) {
  const int per_b = MCELLS / 8;   // 2^18
  int t = blockIdx.x * 256 + threadIdx.x;
  if (t >= B * per_b) return;
  int b = t >> 18;
  int r = t & (per_b - 1);
  int zg = r & 15, y = (r >> 4) & 127, x = r >> 11;
  int z0 = zg << 3;
  int v = (x << 14) | (y << 7) | z0;
  size_t cell = (size_t)b * MCELLS + v;

  const float* ex = eps + (size_t)(b * 4 + 0) * MCELLS;
  const float* ey = eps + (size_t)(b * 4 + 1) * MCELLS;
  const float* ez = eps + (size_t)(b * 4 + 2) * MCELLS;
  const float* lm = eps + (size_t)(b * 4 + 3) * MCELLS;

  float exA[8], eyA[8], ezA9[9], lA[8], qA[8], xmA[8], ymA[8];
  *(float4*)(exA)     = *(const float4*)(ex + v);
  *(float4*)(exA + 4) = *(const float4*)(ex + v + 4);
  *(float4*)(eyA)     = *(const float4*)(ey + v);
  *(float4*)(eyA + 4) = *(const float4*)(ey + v + 4);
  *(float4*)(ezA9 + 1) = *(const float4*)(ez + v);
  *(float4*)(ezA9 + 5) = *(const float4*)(ez + v + 4);
  ezA9[0] = (z0 > 0) ? ez[v - 1] : 0.0f;
  *(float4*)(lA)     = *(const float4*)(lm + v);
  *(float4*)(lA + 4) = *(const float4*)(lm + v + 4);
  *(float4*)(qA)     = *(const float4*)(q + cell);
  *(float4*)(qA + 4) = *(const float4*)(q + cell + 4);
  if (x > 0) {
    *(float4*)(xmA)     = *(const float4*)(ex + v - 16384);
    *(float4*)(xmA + 4) = *(const float4*)(ex + v - 16384 + 4);
  } else {
#pragma unroll
    for (int i = 0; i < 8; ++i) xmA[i] = 0.0f;
  }
  if (y > 0) {
    *(float4*)(ymA)     = *(const float4*)(ey + v - 128);
    *(float4*)(ymA + 4) = *(const float4*)(ey + v - 128 + 4);
  } else {
#pragma unroll
    for (int i = 0; i < 8; ++i) ymA[i] = 0.0f;
  }

  float rdA[8], rqA[8];
  bool pu = true;
#pragma unroll
  for (int i = 0; i < 8; ++i) {
    float den = exA[i] + xmA[i] + eyA[i] + ymA[i] + ezA9[i + 1] + ezA9[i] +
                0.106f * lA[i];
    rdA[i] = __builtin_amdgcn_rcpf(den);
    rqA[i] = qA[i] * rdA[i];
    pu &= (exA[i] == 79.0f) & (eyA[i] == 79.0f) & (ezA9[i + 1] == 79.0f) &
          (lA[i] == 0.0f) & (qA[i] == 0.0f);
  }
  *(uint4*)(exb + cell) = pk8(exA);
  *(uint4*)(eyb + cell) = pk8(eyA);
  *(uint4*)(ezb + cell) = pk8(ezA9 + 1);
  *(uint4*)(rdn + cell) = pk8(rdA);
  uint4 rqp = pk8(rqA);
  *(uint4*)(rq2 + cell) = rqp;
  *(uint4*)(phiA + cell) = rqp;   // phi after sweep 1 (phi0 = 0)

  unsigned long long bal = __ballot(pu);
  int lane = threadIdx.x & 63;
  if ((lane & 15) == 0) {
    unsigned m = (unsigned)((bal >> (lane & 48)) & 0xFFFFull);
    pure16[((size_t)b << 14) + (x << 7) + y] = (u16)m;   // bit zg = octet pure
  }
}

// bulk flag per (x, y-quad) for the single final sweep (column-granular)
__global__ __launch_bounds__(256) void flag_kernel(
    const u16* __restrict__ pure16, unsigned char* __restrict__ flags,
    int B) {
  int t = blockIdx.x * 256 + threadIdx.x;
  if (t >= B * 128 * 32) return;
  int b = t >> 12;
  int r = t & 4095;
  int x = r >> 5, yq = r & 31;
  unsigned char f = 0;
  if (x > 0 && x < 127 && yq > 0 && yq < 31) {
    const u16* P = pure16 + ((size_t)b << 14);
    bool ok = true;
    int y0 = yq << 2;
    for (int dx = -1; dx <= 1; ++dx)
      for (int yy = y0 - 1; yy <= y0 + 4; ++yy)
        ok &= (P[(x + dx) * 128 + yy] == 0xFFFFu);
    f = ok ? 1 : 0;
  }
  flags[t] = f;
}

// ---------------------------------------------------------------------------
// Single Jacobi sweep, bf16 in/out, one z-octet per thread. No LDS, no
// barriers: phi neighbor reads hit L1/L2 (x+-1 neighbor blocks are exactly
// 8 block-ids away -> same XCD under round-robin dispatch, so writer/reader
// L2 affinity holds across the sweep ping-pong). Replaces the fused2 pair
// kernel: the fused structure paid 1.375x halo compute + 2 whole-CU
// barriers per pair and was stuck at ~26.5 us/pair (R3-R5 evidence); this
// has 1.0x work and pure TLP.
// Bulk fast path per z-octet: own column + (x-1,y) + (x,y-1) purity
// (covers all six eps faces + lambda + q), z-face fold (m<<1)|1, borders
// excluded (denominator != 474 there).
// ---------------------------------------------------------------------------
__global__ __launch_bounds__(256) void sweep8_kernel(
    const u16* __restrict__ pin, u16* __restrict__ pout,
    const u16* __restrict__ exb, const u16* __restrict__ eyb,
    const u16* __restrict__ ezb, const u16* __restrict__ rdn,
    const u16* __restrict__ rq2, const u16* __restrict__ pure16,
    int units) {
  int t = blockIdx.x * 256 + threadIdx.x;
  if (t >= units) return;
  int b = t >> 18;
  int r = t & ((1 << 18) - 1);
  int zg = r & 15, y = (r >> 4) & 127, x = r >> 11;
  int z0 = zg << 3;
  int v = (x << 14) | (y << 7) | z0;
  size_t cell = (size_t)b * MCELLS + v;

  const u16* P = pure16 + ((size_t)b << 14);
  unsigned m = 0;
  if (x >= 1 && x <= 126 && y >= 1 && y <= 126) {
    m = (unsigned)P[(x << 7) + y] & P[((x - 1) << 7) + y] &
        P[(x << 7) + y - 1];
    m &= (m << 1) | 1u;
  }
  bool bulk = ((m >> zg) & 1) != 0;

  const uint4 z4 = make_uint4(0, 0, 0, 0);
  uint4 pc = *(const uint4*)(pin + cell);
  u16 zmu = (z0 > 0)   ? pin[cell - 1] : (u16)0;
  u16 zpu = (z0 < 120) ? pin[cell + 8] : (u16)0;
  uint4 xp = (x < 127) ? *(const uint4*)(pin + cell + 16384) : z4;
  uint4 xm = (x > 0)   ? *(const uint4*)(pin + cell - 16384) : z4;
  uint4 yp = (y < 127) ? *(const uint4*)(pin + cell + 128) : z4;
  uint4 ym = (y > 0)   ? *(const uint4*)(pin + cell - 128) : z4;

  float pz[10];
  pz[0] = bf2f(zmu); up8(pc, pz + 1); pz[9] = bf2f(zpu);
  float xpA[8], xmA[8], ypA[8], ymA[8];
  up8(xp, xpA); up8(xm, xmA); up8(yp, ypA); up8(ym, ymA);

  float o[8];
  if (bulk) {
    float rdc  = bf2f(f2bf(__builtin_amdgcn_rcpf(474.0f)));   // 6*79
    float rdc0 = bf2f(f2bf(__builtin_amdgcn_rcpf(395.0f)));   // z=0
#pragma unroll
    for (int i = 0; i < 8; ++i) {
      float s = xpA[i] + xmA[i] + ypA[i] + ymA[i] + pz[i] + pz[i + 2];
      float rd = (z0 + i == 0) ? rdc0 : rdc;
      o[i] = rd * (79.0f * s);
    }
  } else {
    uint4 ec  = *(const uint4*)(exb + cell);
    uint4 em  = (x > 0) ? *(const uint4*)(exb + cell - 16384) : z4;
    uint4 yc  = *(const uint4*)(eyb + cell);
    uint4 ym4 = (y > 0) ? *(const uint4*)(eyb + cell - 128) : z4;
    uint4 zc  = *(const uint4*)(ezb + cell);
    u16 ezm0  = (z0 > 0) ? ezb[cell - 1] : (u16)0;
    uint4 rd4 = *(const uint4*)(rdn + cell);
    uint4 rq4 = *(const uint4*)(rq2 + cell);
    float exA[8], exmA[8], eyA[8], eymA[8], ezA[9], rdA[8], rqA[8];
    up8(ec, exA); up8(em, exmA); up8(yc, eyA); up8(ym4, eymA);
    ezA[0] = bf2f(ezm0); up8(zc, ezA + 1);
    up8(rd4, rdA); up8(rq4, rqA);
#pragma unroll
    for (int i = 0; i < 8; ++i) {
      float num = exA[i] * xpA[i];
      num = fmaf(exmA[i], xmA[i], num);
      num = fmaf(eyA[i],  ypA[i], num);
      num = fmaf(eymA[i], ymA[i], num);
      num = fmaf(ezA[i + 1], pz[i + 2], num);
      num = fmaf(ezA[i],     pz[i],     num);
      o[i] = fmaf(rdA[i], num, rqA[i]);
    }
  }
  *(uint4*)(pout + cell) = pk8(o);
}

// ---------------------------------------------------------------------------
// Single sweep (final): fp32 write to d_out.
// ---------------------------------------------------------------------------
__global__ __launch_bounds__(256) void sweep_final_kernel(
    const u16* __restrict__ pin, float* __restrict__ poutf,
    const u16* __restrict__ exb, const u16* __restrict__ eyb,
    const u16* __restrict__ ezb, const u16* __restrict__ rdn,
    const u16* __restrict__ rq2, const unsigned char* __restrict__ flags,
    int units) {
  int t = blockIdx.x * 256 + threadIdx.x;
  if (t >= units) return;
  int b = t >> 18;
  int r = t & ((1 << 18) - 1);
  int zg = r & 15, y = (r >> 4) & 127, x = r >> 11;
  int z0 = zg << 3;
  int v = (x << 14) | (y << 7) | z0;
  size_t cell = (size_t)b * MCELLS + v;

  const uint4 z4 = make_uint4(0, 0, 0, 0);
  uint4 pc = *(const uint4*)(pin + cell);
  u16 zmu = (z0 > 0)   ? pin[cell - 1] : (u16)0;
  u16 zpu = (z0 < 120) ? pin[cell + 8] : (u16)0;
  uint4 xp = (x < 127) ? *(const uint4*)(pin + cell + 16384) : z4;
  uint4 xm = (x > 0)   ? *(const uint4*)(pin + cell - 16384) : z4;
  uint4 yp = (y < 127) ? *(const uint4*)(pin + cell + 128) : z4;
  uint4 ym = (y > 0)   ? *(const uint4*)(pin + cell - 128) : z4;

  float pz[10];
  pz[0] = bf2f(zmu); up8(pc, pz + 1); pz[9] = bf2f(zpu);
  float xpA[8], xmA[8], ypA[8], ymA[8];
  up8(xp, xpA); up8(xm, xmA); up8(yp, ypA); up8(ym, ymA);

  bool bulk = flags[(b << 12) + (x << 5) + (y >> 2)] != 0;

  float o[8];
  if (bulk) {
    float rdc  = bf2f(f2bf(__builtin_amdgcn_rcpf(474.0f)));
    float rdc0 = bf2f(f2bf(__builtin_amdgcn_rcpf(395.0f)));
#pragma unroll
    for (int i = 0; i < 8; ++i) {
      float s = xpA[i] + xmA[i] + ypA[i] + ymA[i] + pz[i] + pz[i + 2];
      float rd = (z0 + i == 0) ? rdc0 : rdc;
      o[i] = rd * (79.0f * s);
    }
  } else {
    uint4 ec  = *(const uint4*)(exb + cell);
    uint4 em  = (x > 0) ? *(const uint4*)(exb + cell - 16384) : z4;
    uint4 yc  = *(const uint4*)(eyb + cell);
    uint4 ym4 = (y > 0) ? *(const uint4*)(eyb + cell - 128) : z4;
    uint4 zc  = *(const uint4*)(ezb + cell);
    u16 ezm0  = (z0 > 0) ? ezb[cell - 1] : (u16)0;
    uint4 rd4 = *(const uint4*)(rdn + cell);
    uint4 rq4 = *(const uint4*)(rq2 + cell);
    float exA[8], exmA[8], eyA[8], eymA[8], ezA[9], rdA[8], rqA[8];
    up8(ec, exA); up8(em, exmA); up8(yc, eyA); up8(ym4, eymA);
    ezA[0] = bf2f(ezm0); up8(zc, ezA + 1);
    up8(rd4, rdA); up8(rq4, rqA);
#pragma unroll
    for (int i = 0; i < 8; ++i) {
      float num = exA[i] * xpA[i];
      num = fmaf(exmA[i], xmA[i], num);
      num = fmaf(eyA[i],  ypA[i], num);
      num = fmaf(eymA[i], ymA[i], num);
      num = fmaf(ezA[i + 1], pz[i + 2], num);
      num = fmaf(ezA[i],     pz[i],     num);
      o[i] = fmaf(rdA[i], num, rqA[i]);
    }
  }
  *(float4*)(poutf + cell)     = make_float4(o[0], o[1], o[2], o[3]);
  *(float4*)(poutf + cell + 4) = make_float4(o[4], o[5], o[6], o[7]);
}

// ---------------------------------------------------------------------------
// Fallback fp32 Jacobi (tiny ws)
// ---------------------------------------------------------------------------
__global__ __launch_bounds__(256) void jacobi_kernel(
    const float* __restrict__ phi_in, float* __restrict__ phi_out,
    const float* __restrict__ eps, const float* __restrict__ rhs, int B) {
  int i = blockIdx.x * blockDim.x + threadIdx.x;
  if (i >= B * MCELLS) return;
  int b = i >> 21;
  int v = i & (MCELLS - 1);
  int z = v & 127, y = (v >> 7) & 127, x = v >> 14;

  const float* ex = eps + (size_t)(b * 4 + 0) * MCELLS;
  const float* ey = eps + (size_t)(b * 4 + 1) * MCELLS;
  const float* ez = eps + (size_t)(b * 4 + 2) * MCELLS;
  const float* lm = eps + (size_t)(b * 4 + 3) * MCELLS;
  const float* p  = phi_in + (size_t)b * MCELLS;

  float exc = ex[v], eyc = ey[v], ezc = ez[v];
  float exm = (x > 0) ? ex[v - BOX * BOX] : 0.0f;
  float eym = (y > 0) ? ey[v - BOX]       : 0.0f;
  float ezm = (z > 0) ? ez[v - 1]         : 0.0f;

  float num = rhs[i];
  num += (x < BOX - 1) ? exc * p[v + BOX * BOX] : 0.0f;
  num += (x > 0)       ? exm * p[v - BOX * BOX] : 0.0f;
  num += (y < BOX - 1) ? eyc * p[v + BOX]       : 0.0f;
  num += (y > 0)       ? eym * p[v - BOX]       : 0.0f;
  num += (z < BOX - 1) ? ezc * p[v + 1]         : 0.0f;
  num += (z > 0)       ? ezm * p[v - 1]         : 0.0f;

  float den = exc + exm + eyc + eym + ezc + ezm + 0.106f * lm[v];
  phi_out[i] = num / den;
}

// ---------------------------------------------------------------------------
extern "C" void kernel_launch(void* const* d_in, const int* in_sizes, int n_in,
                              void* d_out, int out_size, void* d_ws,
                              size_t ws_size, hipStream_t stream) {
  const float* coords    = (const float*)d_in[0];
  const float* params    = (const float*)d_in[1];
  const int*   num_atoms = (const int*)d_in[2];

  const int B = in_sizes[2];
  const int N = in_sizes[1] / (2 * B);

  float* out = (float*)d_out;
  float* q   = out;                            // (B, M)
  float* eps = out + (size_t)B * MCELLS;       // (B, 4, M)
  float* phi = out + (size_t)B * MCELLS * 5;   // (B, M)

  const size_t BM = (size_t)B * MCELLS;
  u16* phiA = (u16*)d_ws;
  u16* phiB = phiA + BM;
  u16* exb  = phiB + BM;
  u16* eyb  = exb + BM;
  u16* ezb  = eyb + BM;
  u16* rdn  = ezb + BM;
  u16* rq2  = rdn + BM;
  u16* pure16 = rq2 + BM;                       // (B, 128,128) u16 masks
  unsigned char* flags = (unsigned char*)(pure16 + (size_t)B * 16384);
  const size_t need = BM * 14 + (size_t)B * (32768 + 4096);

  const bool fast = (ws_size >= need);

  hipMemsetAsync(q, 0, sizeof(float) * BM, stream);   // scatter accumulator

  eps_gather_kernel<<<dim3(16, 16, 16 * B), 256, 0, stream>>>(
      coords, params, num_atoms, eps, N);
  q_scatter_kernel<<<(B * N + 255) / 256, 256, 0, stream>>>(
      coords, params, num_atoms, q, N, B);

  if (fast) {
    const int pblocks = B * 1024;
    prep8_kernel<<<pblocks, 256, 0, stream>>>(eps, q, exb, eyb, ezb, rdn, rq2,
                                              phiA, pure16, B);
    flag_kernel<<<(B * 4096 + 255) / 256, 256, 0, stream>>>(pure16, flags, B);

    // prep did sweep 1 (phi1 in phiA). 28 single sweeps = sweeps 2..29,
    // ping-pong A->B->...->A (phi29 ends in A). Final sweep 30 -> fp32 out.
    const int units8 = B * (MCELLS / 8);
    u16* pa = phiA;
    u16* pb = phiB;
    for (int k = 0; k < 28; ++k) {
      sweep8_kernel<<<(units8 + 255) / 256, 256, 0, stream>>>(
          pa, pb, exb, eyb, ezb, rdn, rq2, pure16, units8);
      u16* tmp = pa; pa = pb; pb = tmp;
    }
    sweep_final_kernel<<<(units8 + 255) / 256, 256, 0, stream>>>(
        pa, phi, exb, eyb, ezb, rdn, rq2, flags, units8);
  } else {
    hipMemsetAsync(phi, 0, sizeof(float) * BM, stream);
    float* pa = phi;
    float* pb = (float*)d_ws;
    int total = (int)BM;
    for (int it = 0; it < 30; ++it) {
      jacobi_kernel<<<(total + 255) / 256, 256, 0, stream>>>(pa, pb, eps, q, B);
      float* tmp = pa; pa = pb; pb = tmp;
    }
  }
}

// Round 7
// 546.904 us; speedup vs baseline: 1.2343x; 1.2343x over previous
//
#include <hip/hip_runtime.h>
#include <math.h>

#define BOX 128
#define MCELLS (BOX*BOX*BOX)
#define TABN 512
#define SATN 256
typedef unsigned short u16;

__device__ __forceinline__ float bf2f(u16 h) {
  union { unsigned u; float f; } c; c.u = ((unsigned)h) << 16; return c.f;
}
__device__ __forceinline__ u16 f2bf(float f) {
  union { float f; unsigned u; } c; c.f = f;
  unsigned r = c.u + 0x7FFF + ((c.u >> 16) & 1);   // RNE
  return (u16)(r >> 16);
}
__device__ __forceinline__ unsigned pk2(float a, float b) {
  return (unsigned)f2bf(a) | ((unsigned)f2bf(b) << 16);
}
__device__ __forceinline__ float plo(unsigned p) {
  union { unsigned u; float f; } c; c.u = p << 16; return c.f;
}
__device__ __forceinline__ float phh(unsigned p) {
  union { unsigned u; float f; } c; c.u = p & 0xFFFF0000u; return c.f;
}
__device__ __forceinline__ void up8(uint4 p, float* o) {
  o[0] = plo(p.x); o[1] = phh(p.x); o[2] = plo(p.y); o[3] = phh(p.y);
  o[4] = plo(p.z); o[5] = phh(p.z); o[6] = plo(p.w); o[7] = phh(p.w);
}
__device__ __forceinline__ uint4 pk8(const float* o) {
  return make_uint4(pk2(o[0], o[1]), pk2(o[2], o[3]),
                    pk2(o[4], o[5]), pk2(o[6], o[7]));
}

// direct global->LDS 16B copy (dest = wave-uniform base + lane*16 here)
__device__ __forceinline__ void gload_lds16(const u16* g, u16* l) {
  __builtin_amdgcn_global_load_lds(
      (const __attribute__((address_space(1))) unsigned int*)(g),
      (__attribute__((address_space(3))) unsigned int*)(l), 16, 0, 0);
}

// f(u) = log(clip(0.5*(1+erf(u)))) — table builder only
__device__ __forceinline__ float f_exact(float u) {
  float au = fabsf(u);
  float tt = __builtin_amdgcn_rcpf(fmaf(0.3275911f, au, 1.0f));
  float poly = tt * fmaf(tt, fmaf(tt, fmaf(tt, fmaf(tt, 1.061405429f,
                   -1.453152027f), 1.421413741f), -0.284496736f),
                   0.254829592f);
  float e = fmaf(-poly, __expf(-u * u), 1.0f);
  float erfu = (u < 0.0f) ? -e : e;
  float s = fmaf(0.5f, erfu, 0.5f);
  s = fminf(fmaxf(s, 1e-6f), 1.0f);
  return __logf(s);
}

// table over u in [-1.8, 2.2); last bin EXACTLY zero (bulk invariant).
__device__ __forceinline__ float tlookf(const float2* __restrict__ ftab,
                                        float r2, float aoff, float hidu) {
  float r = __builtin_amdgcn_sqrtf(r2);
  float t = fmaf(r, hidu, aoff);
  t = fminf(fmaxf(t, 0.0f), 511.75f);
  int j = (int)t;
  float fr = t - (float)j;
  float2 e = ftab[j];
  return fmaf(fr, e.y, e.x);
}

// ---------------------------------------------------------------------------
// Stage A (gather): one block per 8x8x8 tile, 2 z-cells/thread.
// ---------------------------------------------------------------------------
__global__ __launch_bounds__(256) void eps_gather_kernel(
    const float* __restrict__ coords, const float* __restrict__ params,
    const int* __restrict__ num_atoms, float* __restrict__ eps_out, int N) {
  __shared__ float4 satA[SATN];
  __shared__ float  satW[SATN];
  __shared__ float2 ftab[TABN];
  __shared__ int scnt;

  const int xt = blockIdx.x, yt = blockIdx.y;
  const int bz = blockIdx.z;
  const int b = bz >> 4, zt = bz & 15;
  const int tid = threadIdx.x;

  const float u0 = -1.8f;
  const float du = (2.2f - u0) / (float)TABN;
  const float inv_du = (float)TABN / (2.2f - u0);
  const float hidu = 0.5f * inv_du;
  const float dAI = 0.2f * inv_du;

  if (tid == 0) scnt = 0;
  __syncthreads();

  const float lox = (float)(xt * 8), hix = lox + 7.5f;
  const float loy = (float)(yt * 8), hiy = loy + 7.5f;
  const float loz = (float)(zt * 8), hiz = loz + 7.5f;

  const int na = num_atoms[b];
  for (int a = tid; a < N; a += 256) {
    if (a < na) {
      float ax = coords[(size_t)b * 3 * N + a * 3 + 0];
      float ay = coords[(size_t)b * 3 * N + a * 3 + 1];
      float az = coords[(size_t)b * 3 * N + a * 3 + 2];
      float rad = params[((size_t)b * N + a) * 2 + 1];
      float cx = fminf(fmaxf(ax, lox), hix);
      float cy = fminf(fmaxf(ay, loy), hiy);
      float cz = fminf(fmaxf(az, loz), hiz);
      float ddx = ax - cx, ddy = ay - cy, ddz = az - cz;
      float cut = rad + 5.85f;            // Rw + 4.4 (u<2.2) + slack
      if (ddx * ddx + ddy * ddy + ddz * ddz < cut * cut) {
        int s = atomicAdd(&scnt, 1);
        if (s < SATN) {
          float Rw = rad + 1.4f;
          float cw = rad + 5.8f;          // Rw + 4.4
          satA[s] = make_float4(ax, ay, az, cw * cw);
          satW[s] = (1.8f - 0.5f * Rw) * inv_du;
        }
      }
    }
  }
  __syncthreads();
  const int cnt = min(scnt, SATN);

  const int zq = tid & 3, yy = (tid >> 2) & 7, xx = tid >> 5;
  const int xi = xt * 8 + xx, yi = yt * 8 + yy, zi = zt * 8 + zq * 2;
  const int v = (xi << 14) + (yi << 7) + zi;
  const size_t eb = (size_t)b * 4 * MCELLS;

  if (cnt == 0) {
    *(float2*)(eps_out + eb + 0 * MCELLS + v) = make_float2(79.0f, 79.0f);
    *(float2*)(eps_out + eb + 1 * MCELLS + v) = make_float2(79.0f, 79.0f);
    *(float2*)(eps_out + eb + 2 * MCELLS + v) = make_float2(79.0f, 79.0f);
    *(float2*)(eps_out + eb + (size_t)3 * MCELLS + v) = make_float2(0.0f, 0.0f);
    return;
  }

  for (int j = tid; j < TABN; j += 256) {
    float uj = fmaf(du, (float)j, u0);
    float f0 = f_exact(uj);
    float f1 = f_exact(uj + du);
    ftab[j] = (j == TABN - 1) ? make_float2(0.0f, 0.0f)
                              : make_float2(f0, f1 - f0);
  }
  __syncthreads();

  const float xf = (float)xi, yf = (float)yi, zf = (float)zi;
  float acc[4][2] = {{0.f, 0.f}, {0.f, 0.f}, {0.f, 0.f}, {0.f, 0.f}};

  for (int j = 0; j < cnt; ++j) {
    float4 A = satA[j];
    float aW = satW[j];
    float dx = xf - A.x, dy = yf - A.y, dzb = zf - A.z;
    float cw2 = A.w;

    float dx2 = dx * dx, dxh = dx + 0.5f, dxh2 = dxh * dxh;
    float dy2 = dy * dy, dyh = dy + 0.5f, dyh2 = dyh * dyh;
    float mdx = fminf(dx2, dxh2);
    float mdy = fminf(dy2, dyh2);
    float zhi = dzb + 1.5f;
    float mdz = (dzb > 0.f) ? dzb * dzb : (zhi < 0.f ? zhi * zhi : 0.f);
    if (mdx + mdy + mdz >= cw2) continue;

    float aI = aW + dAI;
    float sW0 = dxh2 + dy2, sW1 = dx2 + dyh2, sxy = dx2 + dy2;
#pragma unroll
    for (int k = 0; k < 2; ++k) {
      float dzv = dzb + (float)k;
      float dz2 = dzv * dzv, dzh = dzv + 0.5f, dzh2 = dzh * dzh;
      acc[0][k] += tlookf(ftab, sW0 + dz2, aW, hidu);
      acc[1][k] += tlookf(ftab, sW1 + dz2, aW, hidu);
      acc[2][k] += tlookf(ftab, sxy + dzh2, aW, hidu);
      acc[3][k] += tlookf(ftab, sxy + dz2, aI, hidu);
    }
  }

#pragma unroll
  for (int ch = 0; ch < 4; ++ch) {
    float e0 = __expf(acc[ch][0]), e1 = __expf(acc[ch][1]);
    float2 o = (ch < 3)
        ? make_float2(fmaf(72.5f, e0, 6.5f), fmaf(72.5f, e1, 6.5f))
        : make_float2(1.0f - e0, 1.0f - e1);
    *(float2*)(eps_out + eb + (size_t)ch * MCELLS + v) = o;
  }
}

// ---------------------------------------------------------------------------
// Stage B: trilinear charge scatter (CHARGE_CONV folded in).
// ---------------------------------------------------------------------------
__global__ __launch_bounds__(256) void q_scatter_kernel(
    const float* __restrict__ coords, const float* __restrict__ params,
    const int* __restrict__ num_atoms, float* __restrict__ q, int N, int B) {
  int t = blockIdx.x * blockDim.x + threadIdx.x;
  if (t >= B * N) return;
  int b = t / N, atom = t % N;
  if (atom >= num_atoms[b]) return;

  const float x = coords[(size_t)b * 3 * N + atom * 3 + 0];
  const float y = coords[(size_t)b * 3 * N + atom * 3 + 1];
  const float z = coords[(size_t)b * 3 * N + atom * 3 + 2];
  const float c = params[((size_t)b * N + atom) * 2 + 0] * 7046.52f;

  float fx0 = floorf(x), fy0 = floorf(y), fz0 = floorf(z);
  int ix = (int)fx0, iy = (int)fy0, iz = (int)fz0;
  float fx = x - fx0, fy = y - fy0, fz = z - fz0;

  float* __restrict__ g = q + (size_t)b * MCELLS;
  for (int k = 0; k < 8; ++k) {
    int cx = (k >> 2) & 1, cy = (k >> 1) & 1, cz = k & 1;
    int jx = ix + cx, jy = iy + cy, jz = iz + cz;
    if ((unsigned)jx >= (unsigned)BOX || (unsigned)jy >= (unsigned)BOX ||
        (unsigned)jz >= (unsigned)BOX) continue;
    float w = (cx ? fx : 1.0f - fx) * (cy ? fy : 1.0f - fy) *
              (cz ? fz : 1.0f - fz);
    atomicAdd(&g[(jx * BOX + jy) * BOX + jz], w * c);
  }
}

// ---------------------------------------------------------------------------
// Prep (8 cells/thread): reads fp32 eps + q (coalesced); writes the MERGED
// per-unit 80B coefficient chunk [ex8|ey8|ez8|rd8|rq8] (unit id == thread
// id: (b<<18)|(x<<11)|(y<<4)|zg — 5 scattered 16B streams -> one contiguous
// 80B chunk, wave writes 5KB dense), phiA = rq (sweep 1), and per-column
// 16-bit purity masks (bit zg = z-octet pure).
// ---------------------------------------------------------------------------
__global__ __launch_bounds__(256) void prep8_kernel(
    const float* __restrict__ eps, const float* __restrict__ q,
    u16* __restrict__ mrg, u16* __restrict__ phiA,
    u16* __restrict__ pure16, int B) {
  const int per_b = MCELLS / 8;   // 2^18
  int t = blockIdx.x * 256 + threadIdx.x;
  if (t >= B * per_b) return;
  int b = t >> 18;
  int r = t & (per_b - 1);
  int zg = r & 15, y = (r >> 4) & 127, x = r >> 11;
  int z0 = zg << 3;
  int v = (x << 14) | (y << 7) | z0;
  size_t cell = (size_t)b * MCELLS + v;

  const float* ex = eps + (size_t)(b * 4 + 0) * MCELLS;
  const float* ey = eps + (size_t)(b * 4 + 1) * MCELLS;
  const float* ez = eps + (size_t)(b * 4 + 2) * MCELLS;
  const float* lm = eps + (size_t)(b * 4 + 3) * MCELLS;

  float exA[8], eyA[8], ezA9[9], lA[8], qA[8], xmA[8], ymA[8];
  *(float4*)(exA)     = *(const float4*)(ex + v);
  *(float4*)(exA + 4) = *(const float4*)(ex + v + 4);
  *(float4*)(eyA)     = *(const float4*)(ey + v);
  *(float4*)(eyA + 4) = *(const float4*)(ey + v + 4);
  *(float4*)(ezA9 + 1) = *(const float4*)(ez + v);
  *(float4*)(ezA9 + 5) = *(const float4*)(ez + v + 4);
  ezA9[0] = (z0 > 0) ? ez[v - 1] : 0.0f;
  *(float4*)(lA)     = *(const float4*)(lm + v);
  *(float4*)(lA + 4) = *(const float4*)(lm + v + 4);
  *(float4*)(qA)     = *(const float4*)(q + cell);
  *(float4*)(qA + 4) = *(const float4*)(q + cell + 4);
  if (x > 0) {
    *(float4*)(xmA)     = *(const float4*)(ex + v - 16384);
    *(float4*)(xmA + 4) = *(const float4*)(ex + v - 16384 + 4);
  } else {
#pragma unroll
    for (int i = 0; i < 8; ++i) xmA[i] = 0.0f;
  }
  if (y > 0) {
    *(float4*)(ymA)     = *(const float4*)(ey + v - 128);
    *(float4*)(ymA + 4) = *(const float4*)(ey + v - 128 + 4);
  } else {
#pragma unroll
    for (int i = 0; i < 8; ++i) ymA[i] = 0.0f;
  }

  float rdA[8], rqA[8];
  bool pu = true;
#pragma unroll
  for (int i = 0; i < 8; ++i) {
    float den = exA[i] + xmA[i] + eyA[i] + ymA[i] + ezA9[i + 1] + ezA9[i] +
                0.106f * lA[i];
    rdA[i] = __builtin_amdgcn_rcpf(den);
    rqA[i] = qA[i] * rdA[i];
    pu &= (exA[i] == 79.0f) & (eyA[i] == 79.0f) & (ezA9[i + 1] == 79.0f) &
          (lA[i] == 0.0f) & (qA[i] == 0.0f);
  }
  u16* m = mrg + (size_t)t * 40;
  *(uint4*)(m)      = pk8(exA);
  *(uint4*)(m + 8)  = pk8(eyA);
  *(uint4*)(m + 16) = pk8(ezA9 + 1);
  *(uint4*)(m + 24) = pk8(rdA);
  uint4 rqp = pk8(rqA);
  *(uint4*)(m + 32) = rqp;
  *(uint4*)(phiA + cell) = rqp;   // phi after sweep 1 (phi0 = 0)

  unsigned long long bal = __ballot(pu);
  int lane = threadIdx.x & 63;
  if ((lane & 15) == 0) {
    unsigned mm = (unsigned)((bal >> (lane & 48)) & 0xFFFFull);
    pure16[((size_t)b << 14) + (x << 7) + y] = (u16)mm;  // bit zg = octet pure
  }
}

// bulk flag per (x, y-quad) for the single final sweep (column-granular)
__global__ __launch_bounds__(256) void flag_kernel(
    const u16* __restrict__ pure16, unsigned char* __restrict__ flags,
    int B) {
  int t = blockIdx.x * 256 + threadIdx.x;
  if (t >= B * 128 * 32) return;
  int b = t >> 12;
  int r = t & 4095;
  int x = r >> 5, yq = r & 31;
  unsigned char f = 0;
  if (x > 0 && x < 127 && yq > 0 && yq < 31) {
    const u16* P = pure16 + ((size_t)b << 14);
    bool ok = true;
    int y0 = yq << 2;
    for (int dx = -1; dx <= 1; ++dx)
      for (int yy = y0 - 1; yy <= y0 + 4; ++yy)
        ok &= (P[(x + dx) * 128 + yy] == 0xFFFFu);
    f = ok ? 1 : 0;
  }
  flags[t] = f;
}

// ---------------------------------------------------------------------------
// 8-z-cell stencil step: phi from LDS tile, coefficients from the merged
// 80B chunk (unit = (b<<18)|(gx<<11)|(gy<<4)|zc): own chunk contiguous,
// em = ex of unit-2048 (x-1), ym4 = ey of unit-16 (y-1), ezm0 = ez elem 7
// of unit-1. 7 scattered request sites -> 3 bases.
// ---------------------------------------------------------------------------
__device__ __forceinline__ void stage8(
    const u16* __restrict__ sp, int cst, int c0, int z0, size_t unit,
    int gx, int gy, bool bulk, const u16* __restrict__ mrg, float* o) {
  const u16* pc0 = sp + (c0 << 7) + z0;
  uint4 pc = *(const uint4*)pc0;
  u16 zmu = (z0 > 0)   ? pc0[-1] : (u16)0;
  u16 zpu = (z0 < 120) ? pc0[8]  : (u16)0;
  uint4 xp = *(const uint4*)(pc0 + (cst << 7));
  uint4 xm = *(const uint4*)(pc0 - (cst << 7));
  uint4 yp = *(const uint4*)(pc0 + 128);
  uint4 ym = *(const uint4*)(pc0 - 128);

  float pz[10];
  pz[0] = bf2f(zmu); up8(pc, pz + 1); pz[9] = bf2f(zpu);
  float xpA[8], xmA[8], ypA[8], ymA[8];
  up8(xp, xpA); up8(xm, xmA); up8(yp, ypA); up8(ym, ymA);

  if (bulk) {
    float rdc  = bf2f(f2bf(__builtin_amdgcn_rcpf(474.0f)));   // 6*79
    float rdc0 = bf2f(f2bf(__builtin_amdgcn_rcpf(395.0f)));   // z=0
#pragma unroll
    for (int i = 0; i < 8; ++i) {
      float s = xpA[i] + xmA[i] + ypA[i] + ymA[i] + pz[i] + pz[i + 2];
      float rd = (z0 + i == 0) ? rdc0 : rdc;
      o[i] = rd * (79.0f * s);
    }
  } else {
    const uint4 z4 = make_uint4(0, 0, 0, 0);
    const u16* m = mrg + unit * 40;
    uint4 ec  = *(const uint4*)(m);
    uint4 em  = (gx > 0) ? *(const uint4*)(m - 40 * 2048) : z4;
    uint4 yc  = *(const uint4*)(m + 8);
    uint4 ym4 = (gy > 0) ? *(const uint4*)(m + 8 - 40 * 16) : z4;
    uint4 zc  = *(const uint4*)(m + 16);
    u16 ezm0  = (z0 > 0) ? m[23 - 40] : (u16)0;
    uint4 rd4 = *(const uint4*)(m + 24);
    uint4 rq4 = *(const uint4*)(m + 32);
    float exA[8], exmA[8], eyA[8], eymA[8], ezA[9], rdA[8], rqA[8];
    up8(ec, exA); up8(em, exmA); up8(yc, eyA); up8(ym4, eymA);
    ezA[0] = bf2f(ezm0); up8(zc, ezA + 1);
    up8(rd4, rdA); up8(rq4, rqA);
#pragma unroll
    for (int i = 0; i < 8; ++i) {
      float num = exA[i] * xpA[i];
      num = fmaf(exmA[i], xmA[i], num);
      num = fmaf(eyA[i],  ypA[i], num);
      num = fmaf(eymA[i], ymA[i], num);
      num = fmaf(ezA[i + 1], pz[i + 2], num);
      num = fmaf(ezA[i],     pz[i],     num);
      o[i] = fmaf(rdA[i], num, rqA[i]);
    }
  }
}

// ---------------------------------------------------------------------------
// Fused double sweep (R5 known-good structure), merged-chunk coefficients.
// s0 12x8x128 + s1 10x6x128 = ~40 KB LDS, 4 blocks/CU. gload_lds fill,
// octet-granular bulk masks, stage1 corner skip.
// ---------------------------------------------------------------------------
__global__ __launch_bounds__(256, 4) void fused2_kernel(
    const u16* __restrict__ pin, u16* __restrict__ pout,
    const u16* __restrict__ mrg, const u16* __restrict__ pure16,
    const u16* __restrict__ zb) {
  __shared__ u16 s0[12 * 8 * 128];
  __shared__ u16 s1[10 * 6 * 128];
  __shared__ u16 sbulk16[96];

  const int flat = blockIdx.x;
  const int xcd = flat & 7;
  const int idx = flat >> 3;
  const int x0 = ((xcd << 1) | (idx & 1)) * 8;   // 16 x-tiles, 2 per XCD
  const int rem = idx >> 1;
  const int y0 = (rem & 31) * 4;                 // 32 y-tiles
  const int b = rem >> 5;

  const int tid = threadIdx.x;
  const size_t bbase = (size_t)b << 21;
  const size_t ubase = (size_t)b << 18;
  const uint4 z4 = make_uint4(0, 0, 0, 0);

  // phi 12x8x128 straight to LDS (OOB columns read the zero scratch)
#pragma unroll
  for (int j = 0; j < 6; ++j) {
    int i = tid + (j << 8);
    int col = i >> 4, zc = i & 15;
    int gx = x0 - 2 + (col >> 3), gy = y0 - 2 + (col & 7);
    const u16* src = (((unsigned)gx < 128u) & ((unsigned)gy < 128u))
        ? (pin + (bbase | ((size_t)gx << 14) | (gy << 7) | (zc << 3)))
        : zb;
    gload_lds16(src, s0 + ((size_t)i << 3));
  }

  // per-column bulk masks for the 12x8 region (self + 4 xy-neighbors pure,
  // per z-octet; then AND with the zg-1 bit for the ez[z0-1] face)
  if (tid < 96) {
    int cx = tid >> 3, cy = tid & 7;
    int gx = x0 - 2 + cx, gy = y0 - 2 + cy;
    unsigned sb = 0;
    if (gx >= 1 && gx <= 126 && gy >= 1 && gy <= 126) {
      const u16* P = pure16 + ((size_t)b << 14);
      sb = (unsigned)P[(gx << 7) + gy] & P[((gx - 1) << 7) + gy] &
           P[((gx + 1) << 7) + gy] & P[(gx << 7) + gy - 1] &
           P[(gx << 7) + gy + 1];
    }
    sbulk16[tid] = (u16)(sb & ((sb << 1) | 1u));
  }
  __syncthreads();

  // stage 1: sweep k+1 on 10x6 minus 4 dead corners -> s1 (bf16)
  for (int u = tid; u < 56 * 16; u += 256) {
    int sidx = u >> 4, zc = u & 15, zz = zc << 3;
    int col = sidx + 1 + (sidx >= 4) + (sidx >= 52);   // skip 0,5,54,59
    int cx = col / 6, cy = col - cx * 6;
    int gx = x0 - 1 + cx, gy = y0 - 1 + cy;
    uint4* dst = (uint4*)(s1 + (col << 7) + zz);
    if ((unsigned)gx >= 128u || (unsigned)gy >= 128u) { *dst = z4; continue; }
    int c0 = (cx + 1) * 8 + (cy + 1);
    size_t unit = ubase | ((size_t)gx << 11) | (gy << 4) | zc;
    float o[8];
    stage8(s0, 8, c0, zz, unit, gx, gy, ((sbulk16[c0] >> zc) & 1) != 0,
           mrg, o);
    *dst = pk8(o);
  }
  __syncthreads();

  // stage 2: sweep k+2 on 8x4 -> global
  for (int u = tid; u < 32 * 16; u += 256) {
    int col = u >> 4, zc = u & 15, zz = zc << 3;
    int cx = col >> 2, cy = col & 3;
    int gx = x0 + cx, gy = y0 + cy;
    int c1 = (cx + 1) * 6 + (cy + 1);
    size_t unit = ubase | ((size_t)gx << 11) | (gy << 4) | zc;
    size_t cell = bbase | (gx << 14) | (gy << 7) | zz;
    float o[8];
    stage8(s1, 6, c1, zz, unit, gx, gy,
           ((sbulk16[(cx + 2) * 8 + (cy + 2)] >> zc) & 1) != 0, mrg, o);
    *(uint4*)(pout + cell) = pk8(o);
  }
}

// ---------------------------------------------------------------------------
// Single sweep (final): fp32 write to d_out, merged-chunk coefficients.
// ---------------------------------------------------------------------------
__global__ __launch_bounds__(256) void sweep_final_kernel(
    const u16* __restrict__ pin, float* __restrict__ poutf,
    const u16* __restrict__ mrg, const unsigned char* __restrict__ flags,
    int units) {
  int t = blockIdx.x * 256 + threadIdx.x;
  if (t >= units) return;
  int b = t >> 18;
  int r = t & ((1 << 18) - 1);
  int zg = r & 15, y = (r >> 4) & 127, x = r >> 11;
  int z0 = zg << 3;
  int v = (x << 14) | (y << 7) | z0;
  size_t cell = (size_t)b * MCELLS + v;

  const uint4 z4 = make_uint4(0, 0, 0, 0);
  uint4 pc = *(const uint4*)(pin + cell);
  u16 zmu = (z0 > 0)   ? pin[cell - 1] : (u16)0;
  u16 zpu = (z0 < 120) ? pin[cell + 8] : (u16)0;
  uint4 xp = (x < 127) ? *(const uint4*)(pin + cell + 16384) : z4;
  uint4 xm = (x > 0)   ? *(const uint4*)(pin + cell - 16384) : z4;
  uint4 yp = (y < 127) ? *(const uint4*)(pin + cell + 128) : z4;
  uint4 ym = (y > 0)   ? *(const uint4*)(pin + cell - 128) : z4;

  float pz[10];
  pz[0] = bf2f(zmu); up8(pc, pz + 1); pz[9] = bf2f(zpu);
  float xpA[8], xmA[8], ypA[8], ymA[8];
  up8(xp, xpA); up8(xm, xmA); up8(yp, ypA); up8(ym, ymA);

  bool bulk = flags[(b << 12) + (x << 5) + (y >> 2)] != 0;

  float o[8];
  if (bulk) {
    float rdc  = bf2f(f2bf(__builtin_amdgcn_rcpf(474.0f)));
    float rdc0 = bf2f(f2bf(__builtin_amdgcn_rcpf(395.0f)));
#pragma unroll
    for (int i = 0; i < 8; ++i) {
      float s = xpA[i] + xmA[i] + ypA[i] + ymA[i] + pz[i] + pz[i + 2];
      float rd = (z0 + i == 0) ? rdc0 : rdc;
      o[i] = rd * (79.0f * s);
    }
  } else {
    const u16* m = mrg + (size_t)t * 40;
    uint4 ec  = *(const uint4*)(m);
    uint4 em  = (x > 0) ? *(const uint4*)(m - 40 * 2048) : z4;
    uint4 yc  = *(const uint4*)(m + 8);
    uint4 ym4 = (y > 0) ? *(const uint4*)(m + 8 - 40 * 16) : z4;
    uint4 zc  = *(const uint4*)(m + 16);
    u16 ezm0  = (z0 > 0) ? m[23 - 40] : (u16)0;
    uint4 rd4 = *(const uint4*)(m + 24);
    uint4 rq4 = *(const uint4*)(m + 32);
    float exA[8], exmA[8], eyA[8], eymA[8], ezA[9], rdA[8], rqA[8];
    up8(ec, exA); up8(em, exmA); up8(yc, eyA); up8(ym4, eymA);
    ezA[0] = bf2f(ezm0); up8(zc, ezA + 1);
    up8(rd4, rdA); up8(rq4, rqA);
#pragma unroll
    for (int i = 0; i < 8; ++i) {
      float num = exA[i] * xpA[i];
      num = fmaf(exmA[i], xmA[i], num);
      num = fmaf(eyA[i],  ypA[i], num);
      num = fmaf(eymA[i], ymA[i], num);
      num = fmaf(ezA[i + 1], pz[i + 2], num);
      num = fmaf(ezA[i],     pz[i],     num);
      o[i] = fmaf(rdA[i], num, rqA[i]);
    }
  }
  *(float4*)(poutf + cell)     = make_float4(o[0], o[1], o[2], o[3]);
  *(float4*)(poutf + cell + 4) = make_float4(o[4], o[5], o[6], o[7]);
}

// ---------------------------------------------------------------------------
// Fallback fp32 Jacobi (tiny ws)
// ---------------------------------------------------------------------------
__global__ __launch_bounds__(256) void jacobi_kernel(
    const float* __restrict__ phi_in, float* __restrict__ phi_out,
    const float* __restrict__ eps, const float* __restrict__ rhs, int B) {
  int i = blockIdx.x * blockDim.x + threadIdx.x;
  if (i >= B * MCELLS) return;
  int b = i >> 21;
  int v = i & (MCELLS - 1);
  int z = v & 127, y = (v >> 7) & 127, x = v >> 14;

  const float* ex = eps + (size_t)(b * 4 + 0) * MCELLS;
  const float* ey = eps + (size_t)(b * 4 + 1) * MCELLS;
  const float* ez = eps + (size_t)(b * 4 + 2) * MCELLS;
  const float* lm = eps + (size_t)(b * 4 + 3) * MCELLS;
  const float* p  = phi_in + (size_t)b * MCELLS;

  float exc = ex[v], eyc = ey[v], ezc = ez[v];
  float exm = (x > 0) ? ex[v - BOX * BOX] : 0.0f;
  float eym = (y > 0) ? ey[v - BOX]       : 0.0f;
  float ezm = (z > 0) ? ez[v - 1]         : 0.0f;

  float num = rhs[i];
  num += (x < BOX - 1) ? exc * p[v + BOX * BOX] : 0.0f;
  num += (x > 0)       ? exm * p[v - BOX * BOX] : 0.0f;
  num += (y < BOX - 1) ? eyc * p[v + BOX]       : 0.0f;
  num += (y > 0)       ? eym * p[v - BOX]       : 0.0f;
  num += (z < BOX - 1) ? ezc * p[v + 1]         : 0.0f;
  num += (z > 0)       ? ezm * p[v - 1]         : 0.0f;

  float den = exc + exm + eyc + eym + ezc + ezm + 0.106f * lm[v];
  phi_out[i] = num / den;
}

// ---------------------------------------------------------------------------
extern "C" void kernel_launch(void* const* d_in, const int* in_sizes, int n_in,
                              void* d_out, int out_size, void* d_ws,
                              size_t ws_size, hipStream_t stream) {
  const float* coords    = (const float*)d_in[0];
  const float* params    = (const float*)d_in[1];
  const int*   num_atoms = (const int*)d_in[2];

  const int B = in_sizes[2];
  const int N = in_sizes[1] / (2 * B);

  float* out = (float*)d_out;
  float* q   = out;                            // (B, M)
  float* eps = out + (size_t)B * MCELLS;       // (B, 4, M)
  float* phi = out + (size_t)B * MCELLS * 5;   // (B, M)

  const size_t BM = (size_t)B * MCELLS;
  u16* phiA = (u16*)d_ws;
  u16* phiB = phiA + BM;
  u16* mrg  = phiB + BM;                        // 5*BM u16 (merged chunks)
  u16* pure16 = mrg + 5 * BM;                   // (B, 128,128) u16 masks
  unsigned char* flags = (unsigned char*)(pure16 + (size_t)B * 16384);
  u16* zb = (u16*)(flags + (size_t)B * 4096);   // 64 B zero scratch
  const size_t need = BM * 14 + (size_t)B * (32768 + 4096) + 64;

  const bool fast = (ws_size >= need);

  hipMemsetAsync(q, 0, sizeof(float) * BM, stream);   // scatter accumulator

  eps_gather_kernel<<<dim3(16, 16, 16 * B), 256, 0, stream>>>(
      coords, params, num_atoms, eps, N);
  q_scatter_kernel<<<(B * N + 255) / 256, 256, 0, stream>>>(
      coords, params, num_atoms, q, N, B);

  if (fast) {
    const int pblocks = B * 1024;
    prep8_kernel<<<pblocks, 256, 0, stream>>>(eps, q, mrg, phiA, pure16, B);
    flag_kernel<<<(B * 4096 + 255) / 256, 256, 0, stream>>>(pure16, flags, B);
    hipMemsetAsync(zb, 0, 64, stream);

    // prep did sweep 1 (phi1 in phiA). 14 fused pairs = sweeps 2..29,
    // ping-pong A->B->A (phi29 ends in A). Final single sweep 30 -> fp32 out.
    u16* pa = phiA;
    u16* pb = phiB;
    for (int k = 0; k < 14; ++k) {
      fused2_kernel<<<512 * B, 256, 0, stream>>>(pa, pb, mrg, pure16, zb);
      u16* tmp = pa; pa = pb; pb = tmp;
    }
    const int units8 = B * (MCELLS / 8);
    sweep_final_kernel<<<(units8 + 255) / 256, 256, 0, stream>>>(
        pa, phi, mrg, flags, units8);
  } else {
    hipMemsetAsync(phi, 0, sizeof(float) * BM, stream);
    float* pa = phi;
    float* pb = (float*)d_ws;
    int total = (int)BM;
    for (int it = 0; it < 30; ++it) {
      jacobi_kernel<<<(total + 255) / 256, 256, 0, stream>>>(pa, pb, eps, q, B);
      float* tmp = pa; pa = pb; pb = tmp;
    }
  }
}

// Round 8
// 431.947 us; speedup vs baseline: 1.5628x; 1.2661x over previous
//
#include <hip/hip_runtime.h>
#include <math.h>

#define BOX 128
#define MCELLS (BOX*BOX*BOX)
#define TABN 512
#define SATN 256
typedef unsigned short u16;

__device__ __forceinline__ float bf2f(u16 h) {
  union { unsigned u; float f; } c; c.u = ((unsigned)h) << 16; return c.f;
}
__device__ __forceinline__ u16 f2bf(float f) {
  union { float f; unsigned u; } c; c.f = f;
  unsigned r = c.u + 0x7FFF + ((c.u >> 16) & 1);   // RNE
  return (u16)(r >> 16);
}
__device__ __forceinline__ unsigned pk2(float a, float b) {
  return (unsigned)f2bf(a) | ((unsigned)f2bf(b) << 16);
}
__device__ __forceinline__ float plo(unsigned p) {
  union { unsigned u; float f; } c; c.u = p << 16; return c.f;
}
__device__ __forceinline__ float phh(unsigned p) {
  union { unsigned u; float f; } c; c.u = p & 0xFFFF0000u; return c.f;
}
__device__ __forceinline__ void up8(uint4 p, float* o) {
  o[0] = plo(p.x); o[1] = phh(p.x); o[2] = plo(p.y); o[3] = phh(p.y);
  o[4] = plo(p.z); o[5] = phh(p.z); o[6] = plo(p.w); o[7] = phh(p.w);
}
__device__ __forceinline__ uint4 pk8(const float* o) {
  return make_uint4(pk2(o[0], o[1]), pk2(o[2], o[3]),
                    pk2(o[4], o[5]), pk2(o[6], o[7]));
}

// direct global->LDS 16B copy (dest = wave-uniform base + lane*16 here)
__device__ __forceinline__ void gload_lds16(const u16* g, u16* l) {
  __builtin_amdgcn_global_load_lds(
      (const __attribute__((address_space(1))) unsigned int*)(g),
      (__attribute__((address_space(3))) unsigned int*)(l), 16, 0, 0);
}

// f(u) = log(clip(0.5*(1+erf(u)))) — table builder only
__device__ __forceinline__ float f_exact(float u) {
  float au = fabsf(u);
  float tt = __builtin_amdgcn_rcpf(fmaf(0.3275911f, au, 1.0f));
  float poly = tt * fmaf(tt, fmaf(tt, fmaf(tt, fmaf(tt, 1.061405429f,
                   -1.453152027f), 1.421413741f), -0.284496736f),
                   0.254829592f);
  float e = fmaf(-poly, __expf(-u * u), 1.0f);
  float erfu = (u < 0.0f) ? -e : e;
  float s = fmaf(0.5f, erfu, 0.5f);
  s = fminf(fmaxf(s, 1e-6f), 1.0f);
  return __logf(s);
}

// table over u in [-1.8, 2.2); last bin EXACTLY zero (bulk invariant).
__device__ __forceinline__ float tlookf(const float2* __restrict__ ftab,
                                        float r2, float aoff, float hidu) {
  float r = __builtin_amdgcn_sqrtf(r2);
  float t = fmaf(r, hidu, aoff);
  t = fminf(fmaxf(t, 0.0f), 511.75f);
  int j = (int)t;
  float fr = t - (float)j;
  float2 e = ftab[j];
  return fmaf(fr, e.y, e.x);
}

// ---------------------------------------------------------------------------
// Stage A (gather): one block per 8x8x8 tile, 2 z-cells/thread.
// ---------------------------------------------------------------------------
__global__ __launch_bounds__(256) void eps_gather_kernel(
    const float* __restrict__ coords, const float* __restrict__ params,
    const int* __restrict__ num_atoms, float* __restrict__ eps_out, int N) {
  __shared__ float4 satA[SATN];
  __shared__ float  satW[SATN];
  __shared__ float2 ftab[TABN];
  __shared__ int scnt;

  const int xt = blockIdx.x, yt = blockIdx.y;
  const int bz = blockIdx.z;
  const int b = bz >> 4, zt = bz & 15;
  const int tid = threadIdx.x;

  const float u0 = -1.8f;
  const float du = (2.2f - u0) / (float)TABN;
  const float inv_du = (float)TABN / (2.2f - u0);
  const float hidu = 0.5f * inv_du;
  const float dAI = 0.2f * inv_du;

  if (tid == 0) scnt = 0;
  __syncthreads();

  const float lox = (float)(xt * 8), hix = lox + 7.5f;
  const float loy = (float)(yt * 8), hiy = loy + 7.5f;
  const float loz = (float)(zt * 8), hiz = loz + 7.5f;

  const int na = num_atoms[b];
  for (int a = tid; a < N; a += 256) {
    if (a < na) {
      float ax = coords[(size_t)b * 3 * N + a * 3 + 0];
      float ay = coords[(size_t)b * 3 * N + a * 3 + 1];
      float az = coords[(size_t)b * 3 * N + a * 3 + 2];
      float rad = params[((size_t)b * N + a) * 2 + 1];
      float cx = fminf(fmaxf(ax, lox), hix);
      float cy = fminf(fmaxf(ay, loy), hiy);
      float cz = fminf(fmaxf(az, loz), hiz);
      float ddx = ax - cx, ddy = ay - cy, ddz = az - cz;
      float cut = rad + 5.85f;            // Rw + 4.4 (u<2.2) + slack
      if (ddx * ddx + ddy * ddy + ddz * ddz < cut * cut) {
        int s = atomicAdd(&scnt, 1);
        if (s < SATN) {
          float Rw = rad + 1.4f;
          float cw = rad + 5.8f;          // Rw + 4.4
          satA[s] = make_float4(ax, ay, az, cw * cw);
          satW[s] = (1.8f - 0.5f * Rw) * inv_du;
        }
      }
    }
  }
  __syncthreads();
  const int cnt = min(scnt, SATN);

  const int zq = tid & 3, yy = (tid >> 2) & 7, xx = tid >> 5;
  const int xi = xt * 8 + xx, yi = yt * 8 + yy, zi = zt * 8 + zq * 2;
  const int v = (xi << 14) + (yi << 7) + zi;
  const size_t eb = (size_t)b * 4 * MCELLS;

  if (cnt == 0) {
    *(float2*)(eps_out + eb + 0 * MCELLS + v) = make_float2(79.0f, 79.0f);
    *(float2*)(eps_out + eb + 1 * MCELLS + v) = make_float2(79.0f, 79.0f);
    *(float2*)(eps_out + eb + 2 * MCELLS + v) = make_float2(79.0f, 79.0f);
    *(float2*)(eps_out + eb + (size_t)3 * MCELLS + v) = make_float2(0.0f, 0.0f);
    return;
  }

  for (int j = tid; j < TABN; j += 256) {
    float uj = fmaf(du, (float)j, u0);
    float f0 = f_exact(uj);
    float f1 = f_exact(uj + du);
    ftab[j] = (j == TABN - 1) ? make_float2(0.0f, 0.0f)
                              : make_float2(f0, f1 - f0);
  }
  __syncthreads();

  const float xf = (float)xi, yf = (float)yi, zf = (float)zi;
  float acc[4][2] = {{0.f, 0.f}, {0.f, 0.f}, {0.f, 0.f}, {0.f, 0.f}};

  for (int j = 0; j < cnt; ++j) {
    float4 A = satA[j];
    float aW = satW[j];
    float dx = xf - A.x, dy = yf - A.y, dzb = zf - A.z;
    float cw2 = A.w;

    float dx2 = dx * dx, dxh = dx + 0.5f, dxh2 = dxh * dxh;
    float dy2 = dy * dy, dyh = dy + 0.5f, dyh2 = dyh * dyh;
    float mdx = fminf(dx2, dxh2);
    float mdy = fminf(dy2, dyh2);
    float zhi = dzb + 1.5f;
    float mdz = (dzb > 0.f) ? dzb * dzb : (zhi < 0.f ? zhi * zhi : 0.f);
    if (mdx + mdy + mdz >= cw2) continue;

    float aI = aW + dAI;
    float sW0 = dxh2 + dy2, sW1 = dx2 + dyh2, sxy = dx2 + dy2;
#pragma unroll
    for (int k = 0; k < 2; ++k) {
      float dzv = dzb + (float)k;
      float dz2 = dzv * dzv, dzh = dzv + 0.5f, dzh2 = dzh * dzh;
      acc[0][k] += tlookf(ftab, sW0 + dz2, aW, hidu);
      acc[1][k] += tlookf(ftab, sW1 + dz2, aW, hidu);
      acc[2][k] += tlookf(ftab, sxy + dzh2, aW, hidu);
      acc[3][k] += tlookf(ftab, sxy + dz2, aI, hidu);
    }
  }

#pragma unroll
  for (int ch = 0; ch < 4; ++ch) {
    float e0 = __expf(acc[ch][0]), e1 = __expf(acc[ch][1]);
    float2 o = (ch < 3)
        ? make_float2(fmaf(72.5f, e0, 6.5f), fmaf(72.5f, e1, 6.5f))
        : make_float2(1.0f - e0, 1.0f - e1);
    *(float2*)(eps_out + eb + (size_t)ch * MCELLS + v) = o;
  }
}

// ---------------------------------------------------------------------------
// Stage B: trilinear charge scatter (CHARGE_CONV folded in).
// ---------------------------------------------------------------------------
__global__ __launch_bounds__(256) void q_scatter_kernel(
    const float* __restrict__ coords, const float* __restrict__ params,
    const int* __restrict__ num_atoms, float* __restrict__ q, int N, int B) {
  int t = blockIdx.x * blockDim.x + threadIdx.x;
  if (t >= B * N) return;
  int b = t / N, atom = t % N;
  if (atom >= num_atoms[b]) return;

  const float x = coords[(size_t)b * 3 * N + atom * 3 + 0];
  const float y = coords[(size_t)b * 3 * N + atom * 3 + 1];
  const float z = coords[(size_t)b * 3 * N + atom * 3 + 2];
  const float c = params[((size_t)b * N + atom) * 2 + 0] * 7046.52f;

  float fx0 = floorf(x), fy0 = floorf(y), fz0 = floorf(z);
  int ix = (int)fx0, iy = (int)fy0, iz = (int)fz0;
  float fx = x - fx0, fy = y - fy0, fz = z - fz0;

  float* __restrict__ g = q + (size_t)b * MCELLS;
  for (int k = 0; k < 8; ++k) {
    int cx = (k >> 2) & 1, cy = (k >> 1) & 1, cz = k & 1;
    int jx = ix + cx, jy = iy + cy, jz = iz + cz;
    if ((unsigned)jx >= (unsigned)BOX || (unsigned)jy >= (unsigned)BOX ||
        (unsigned)jz >= (unsigned)BOX) continue;
    float w = (cx ? fx : 1.0f - fx) * (cy ? fy : 1.0f - fy) *
              (cz ? fz : 1.0f - fz);
    atomicAdd(&g[(jx * BOX + jy) * BOX + jz], w * c);
  }
}

// ---------------------------------------------------------------------------
// Prep (8 cells/thread): reads fp32 eps + q (coalesced); writes bf16 packs
// ex/ey/ez/rd/rq (separate SoA streams — R7's merged AoS layout broke
// per-instruction coalescing, 16B@80B-stride, and regressed 20%), phiA = rq
// (sweep 1), and per-column 16-bit purity masks (bit zg = z-octet pure).
// ---------------------------------------------------------------------------
__global__ __launch_bounds__(256) void prep8_kernel(
    const float* __restrict__ eps, const float* __restrict__ q,
    u16* __restrict__ exb, u16* __restrict__ eyb, u16* __restrict__ ezb,
    u16* __restrict__ rdn, u16* __restrict__ rq2, u16* __restrict__ phiA,
    u16* __restrict__ pure16, int B) {
  const int per_b = MCELLS / 8;   // 2^18
  int t = blockIdx.x * 256 + threadIdx.x;
  if (t >= B * per_b) return;
  int b = t >> 18;
  int r = t & (per_b - 1);
  int zg = r & 15, y = (r >> 4) & 127, x = r >> 11;
  int z0 = zg << 3;
  int v = (x << 14) | (y << 7) | z0;
  size_t cell = (size_t)b * MCELLS + v;

  const float* ex = eps + (size_t)(b * 4 + 0) * MCELLS;
  const float* ey = eps + (size_t)(b * 4 + 1) * MCELLS;
  const float* ez = eps + (size_t)(b * 4 + 2) * MCELLS;
  const float* lm = eps + (size_t)(b * 4 + 3) * MCELLS;

  float exA[8], eyA[8], ezA9[9], lA[8], qA[8], xmA[8], ymA[8];
  *(float4*)(exA)     = *(const float4*)(ex + v);
  *(float4*)(exA + 4) = *(const float4*)(ex + v + 4);
  *(float4*)(eyA)     = *(const float4*)(ey + v);
  *(float4*)(eyA + 4) = *(const float4*)(ey + v + 4);
  *(float4*)(ezA9 + 1) = *(const float4*)(ez + v);
  *(float4*)(ezA9 + 5) = *(const float4*)(ez + v + 4);
  ezA9[0] = (z0 > 0) ? ez[v - 1] : 0.0f;
  *(float4*)(lA)     = *(const float4*)(lm + v);
  *(float4*)(lA + 4) = *(const float4*)(lm + v + 4);
  *(float4*)(qA)     = *(const float4*)(q + cell);
  *(float4*)(qA + 4) = *(const float4*)(q + cell + 4);
  if (x > 0) {
    *(float4*)(xmA)     = *(const float4*)(ex + v - 16384);
    *(float4*)(xmA + 4) = *(const float4*)(ex + v - 16384 + 4);
  } else {
#pragma unroll
    for (int i = 0; i < 8; ++i) xmA[i] = 0.0f;
  }
  if (y > 0) {
    *(float4*)(ymA)     = *(const float4*)(ey + v - 128);
    *(float4*)(ymA + 4) = *(const float4*)(ey + v - 128 + 4);
  } else {
#pragma unroll
    for (int i = 0; i < 8; ++i) ymA[i] = 0.0f;
  }

  float rdA[8], rqA[8];
  bool pu = true;
#pragma unroll
  for (int i = 0; i < 8; ++i) {
    float den = exA[i] + xmA[i] + eyA[i] + ymA[i] + ezA9[i + 1] + ezA9[i] +
                0.106f * lA[i];
    rdA[i] = __builtin_amdgcn_rcpf(den);
    rqA[i] = qA[i] * rdA[i];
    pu &= (exA[i] == 79.0f) & (eyA[i] == 79.0f) & (ezA9[i + 1] == 79.0f) &
          (lA[i] == 0.0f) & (qA[i] == 0.0f);
  }
  *(uint4*)(exb + cell) = pk8(exA);
  *(uint4*)(eyb + cell) = pk8(eyA);
  *(uint4*)(ezb + cell) = pk8(ezA9 + 1);
  *(uint4*)(rdn + cell) = pk8(rdA);
  uint4 rqp = pk8(rqA);
  *(uint4*)(rq2 + cell) = rqp;
  *(uint4*)(phiA + cell) = rqp;   // phi after sweep 1 (phi0 = 0)

  unsigned long long bal = __ballot(pu);
  int lane = threadIdx.x & 63;
  if ((lane & 15) == 0) {
    unsigned m = (unsigned)((bal >> (lane & 48)) & 0xFFFFull);
    pure16[((size_t)b << 14) + (x << 7) + y] = (u16)m;   // bit zg = octet pure
  }
}

// bulk flag per (x, y-quad) for the single final sweep (column-granular)
__global__ __launch_bounds__(256) void flag_kernel(
    const u16* __restrict__ pure16, unsigned char* __restrict__ flags,
    int B) {
  int t = blockIdx.x * 256 + threadIdx.x;
  if (t >= B * 128 * 32) return;
  int b = t >> 12;
  int r = t & 4095;
  int x = r >> 5, yq = r & 31;
  unsigned char f = 0;
  if (x > 0 && x < 127 && yq > 0 && yq < 31) {
    const u16* P = pure16 + ((size_t)b << 14);
    bool ok = true;
    int y0 = yq << 2;
    for (int dx = -1; dx <= 1; ++dx)
      for (int yy = y0 - 1; yy <= y0 + 4; ++yy)
        ok &= (P[(x + dx) * 128 + yy] == 0xFFFFu);
    f = ok ? 1 : 0;
  }
  flags[t] = f;
}

// ---------------------------------------------------------------------------
// 8-z-cell stencil step reading phi from an LDS tile (cst = x-column
// stride in columns; y stride is 1 column = 128 cells).
// ---------------------------------------------------------------------------
__device__ __forceinline__ void stage8(
    const u16* __restrict__ sp, int cst, int c0, int z0, size_t cell,
    int gx, int gy, bool bulk,
    const u16* __restrict__ exb, const u16* __restrict__ eyb,
    const u16* __restrict__ ezb, const u16* __restrict__ rdn,
    const u16* __restrict__ rq2, float* o) {
  const u16* pc0 = sp + (c0 << 7) + z0;
  uint4 pc = *(const uint4*)pc0;
  u16 zmu = (z0 > 0)   ? pc0[-1] : (u16)0;
  u16 zpu = (z0 < 120) ? pc0[8]  : (u16)0;
  uint4 xp = *(const uint4*)(pc0 + (cst << 7));
  uint4 xm = *(const uint4*)(pc0 - (cst << 7));
  uint4 yp = *(const uint4*)(pc0 + 128);
  uint4 ym = *(const uint4*)(pc0 - 128);

  float pz[10];
  pz[0] = bf2f(zmu); up8(pc, pz + 1); pz[9] = bf2f(zpu);
  float xpA[8], xmA[8], ypA[8], ymA[8];
  up8(xp, xpA); up8(xm, xmA); up8(yp, ypA); up8(ym, ymA);

  if (bulk) {
    float rdc  = bf2f(f2bf(__builtin_amdgcn_rcpf(474.0f)));   // 6*79
    float rdc0 = bf2f(f2bf(__builtin_amdgcn_rcpf(395.0f)));   // z=0
#pragma unroll
    for (int i = 0; i < 8; ++i) {
      float s = xpA[i] + xmA[i] + ypA[i] + ymA[i] + pz[i] + pz[i + 2];
      float rd = (z0 + i == 0) ? rdc0 : rdc;
      o[i] = rd * (79.0f * s);
    }
  } else {
    const uint4 z4 = make_uint4(0, 0, 0, 0);
    uint4 ec  = *(const uint4*)(exb + cell);
    uint4 em  = (gx > 0) ? *(const uint4*)(exb + cell - 16384) : z4;
    uint4 yc  = *(const uint4*)(eyb + cell);
    uint4 ym4 = (gy > 0) ? *(const uint4*)(eyb + cell - 128) : z4;
    uint4 zc  = *(const uint4*)(ezb + cell);
    u16 ezm0  = (z0 > 0) ? ezb[cell - 1] : (u16)0;
    uint4 rd4 = *(const uint4*)(rdn + cell);
    uint4 rq4 = *(const uint4*)(rq2 + cell);
    float exA[8], exmA[8], eyA[8], eymA[8], ezA[9], rdA[8], rqA[8];
    up8(ec, exA); up8(em, exmA); up8(yc, eyA); up8(ym4, eymA);
    ezA[0] = bf2f(ezm0); up8(zc, ezA + 1);
    up8(rd4, rdA); up8(rq4, rqA);
#pragma unroll
    for (int i = 0; i < 8; ++i) {
      float num = exA[i] * xpA[i];
      num = fmaf(exmA[i], xmA[i], num);
      num = fmaf(eyA[i],  ypA[i], num);
      num = fmaf(eymA[i], ymA[i], num);
      num = fmaf(ezA[i + 1], pz[i + 2], num);
      num = fmaf(ezA[i],     pz[i],     num);
      o[i] = fmaf(rdA[i], num, rqA[i]);
    }
  }
}

// ---------------------------------------------------------------------------
// Fused double sweep (R5 known-good structure: ~40KB LDS, 4 blocks/CU,
// gload_lds fill, octet bulk masks, stage1 corner skip).
// NEW: balance-aware block->tile mapping. Grid = exactly ONE resident
// generation (1024 = 256 CU x 4), so launch time = slowest CU. The old
// contiguous-slab map gave central XCDs all-heavy (atom-slab) tiles and
// edge XCDs all-bulk tiles. New map: XCD k owns x-tiles {k, k+8} (tile
// heaviness is a bump centered x~64, so h(k)+h(k+8th) is ~constant), and
// each CU's 4 resident blocks (idx bits 5-6 under round-robin issue) span
// both x-tiles and 4 spread y positions. Bijective; y-halo stays in-XCD.
// ---------------------------------------------------------------------------
__global__ __launch_bounds__(256, 4) void fused2_kernel(
    const u16* __restrict__ pin, u16* __restrict__ pout,
    const u16* __restrict__ exb, const u16* __restrict__ eyb,
    const u16* __restrict__ ezb, const u16* __restrict__ rdn,
    const u16* __restrict__ rq2, const u16* __restrict__ pure16,
    const u16* __restrict__ zb) {
  __shared__ u16 s0[12 * 8 * 128];
  __shared__ u16 s1[10 * 6 * 128];
  __shared__ u16 sbulk16[96];

  const int flat = blockIdx.x;
  const int xcd = flat & 7;
  const int idx = flat >> 3;           // [0, 64*B)
  const int gidx = idx & 31;           // per-XCD CU-ish slot
  const int rem = idx >> 5;            // [0, 2*B): bit0=xsel, rest=b
  const int xsel = rem & 1;
  const int b = rem >> 1;
  const int x0 = (xcd + (xsel << 3)) << 3;              // x-tile xcd or xcd+8
  const int y0 = ((gidx + ((rem & 3) << 3)) & 31) << 2; // y spread per slot

  const int tid = threadIdx.x;
  const size_t bbase = (size_t)b << 21;
  const uint4 z4 = make_uint4(0, 0, 0, 0);

  // phi 12x8x128 straight to LDS (OOB columns read the zero scratch)
#pragma unroll
  for (int j = 0; j < 6; ++j) {
    int i = tid + (j << 8);
    int col = i >> 4, zc = i & 15;
    int gx = x0 - 2 + (col >> 3), gy = y0 - 2 + (col & 7);
    const u16* src = (((unsigned)gx < 128u) & ((unsigned)gy < 128u))
        ? (pin + (bbase | ((size_t)gx << 14) | (gy << 7) | (zc << 3)))
        : zb;
    gload_lds16(src, s0 + ((size_t)i << 3));
  }

  // per-column bulk masks for the 12x8 region (self + 4 xy-neighbors pure,
  // per z-octet; then AND with the zg-1 bit for the ez[z0-1] face)
  if (tid < 96) {
    int cx = tid >> 3, cy = tid & 7;
    int gx = x0 - 2 + cx, gy = y0 - 2 + cy;
    unsigned sb = 0;
    if (gx >= 1 && gx <= 126 && gy >= 1 && gy <= 126) {
      const u16* P = pure16 + ((size_t)b << 14);
      sb = (unsigned)P[(gx << 7) + gy] & P[((gx - 1) << 7) + gy] &
           P[((gx + 1) << 7) + gy] & P[(gx << 7) + gy - 1] &
           P[(gx << 7) + gy + 1];
    }
    sbulk16[tid] = (u16)(sb & ((sb << 1) | 1u));
  }
  __syncthreads();

  // stage 1: sweep k+1 on 10x6 minus 4 dead corners -> s1 (bf16)
  for (int u = tid; u < 56 * 16; u += 256) {
    int sidx = u >> 4, zc = u & 15, zz = zc << 3;
    int col = sidx + 1 + (sidx >= 4) + (sidx >= 52);   // skip 0,5,54,59
    int cx = col / 6, cy = col - cx * 6;
    int gx = x0 - 1 + cx, gy = y0 - 1 + cy;
    uint4* dst = (uint4*)(s1 + (col << 7) + zz);
    if ((unsigned)gx >= 128u || (unsigned)gy >= 128u) { *dst = z4; continue; }
    int c0 = (cx + 1) * 8 + (cy + 1);
    size_t cell = bbase | (gx << 14) | (gy << 7) | zz;
    float o[8];
    stage8(s0, 8, c0, zz, cell, gx, gy, ((sbulk16[c0] >> zc) & 1) != 0,
           exb, eyb, ezb, rdn, rq2, o);
    *dst = pk8(o);
  }
  __syncthreads();

  // stage 2: sweep k+2 on 8x4 -> global
  for (int u = tid; u < 32 * 16; u += 256) {
    int col = u >> 4, zc = u & 15, zz = zc << 3;
    int cx = col >> 2, cy = col & 3;
    int gx = x0 + cx, gy = y0 + cy;
    int c1 = (cx + 1) * 6 + (cy + 1);
    size_t cell = bbase | (gx << 14) | (gy << 7) | zz;
    float o[8];
    stage8(s1, 6, c1, zz, cell, gx, gy,
           ((sbulk16[(cx + 2) * 8 + (cy + 2)] >> zc) & 1) != 0,
           exb, eyb, ezb, rdn, rq2, o);
    *(uint4*)(pout + cell) = pk8(o);
  }
}

// ---------------------------------------------------------------------------
// Single sweep (final): fp32 write to d_out.
// ---------------------------------------------------------------------------
__global__ __launch_bounds__(256) void sweep_final_kernel(
    const u16* __restrict__ pin, float* __restrict__ poutf,
    const u16* __restrict__ exb, const u16* __restrict__ eyb,
    const u16* __restrict__ ezb, const u16* __restrict__ rdn,
    const u16* __restrict__ rq2, const unsigned char* __restrict__ flags,
    int units) {
  int t = blockIdx.x * 256 + threadIdx.x;
  if (t >= units) return;
  int b = t >> 18;
  int r = t & ((1 << 18) - 1);
  int zg = r & 15, y = (r >> 4) & 127, x = r >> 11;
  int z0 = zg << 3;
  int v = (x << 14) | (y << 7) | z0;
  size_t cell = (size_t)b * MCELLS + v;

  const uint4 z4 = make_uint4(0, 0, 0, 0);
  uint4 pc = *(const uint4*)(pin + cell);
  u16 zmu = (z0 > 0)   ? pin[cell - 1] : (u16)0;
  u16 zpu = (z0 < 120) ? pin[cell + 8] : (u16)0;
  uint4 xp = (x < 127) ? *(const uint4*)(pin + cell + 16384) : z4;
  uint4 xm = (x > 0)   ? *(const uint4*)(pin + cell - 16384) : z4;
  uint4 yp = (y < 127) ? *(const uint4*)(pin + cell + 128) : z4;
  uint4 ym = (y > 0)   ? *(const uint4*)(pin + cell - 128) : z4;

  float pz[10];
  pz[0] = bf2f(zmu); up8(pc, pz + 1); pz[9] = bf2f(zpu);
  float xpA[8], xmA[8], ypA[8], ymA[8];
  up8(xp, xpA); up8(xm, xmA); up8(yp, ypA); up8(ym, ymA);

  bool bulk = flags[(b << 12) + (x << 5) + (y >> 2)] != 0;

  float o[8];
  if (bulk) {
    float rdc  = bf2f(f2bf(__builtin_amdgcn_rcpf(474.0f)));
    float rdc0 = bf2f(f2bf(__builtin_amdgcn_rcpf(395.0f)));
#pragma unroll
    for (int i = 0; i < 8; ++i) {
      float s = xpA[i] + xmA[i] + ypA[i] + ymA[i] + pz[i] + pz[i + 2];
      float rd = (z0 + i == 0) ? rdc0 : rdc;
      o[i] = rd * (79.0f * s);
    }
  } else {
    uint4 ec  = *(const uint4*)(exb + cell);
    uint4 em  = (x > 0) ? *(const uint4*)(exb + cell - 16384) : z4;
    uint4 yc  = *(const uint4*)(eyb + cell);
    uint4 ym4 = (y > 0) ? *(const uint4*)(eyb + cell - 128) : z4;
    uint4 zc  = *(const uint4*)(ezb + cell);
    u16 ezm0  = (z0 > 0) ? ezb[cell - 1] : (u16)0;
    uint4 rd4 = *(const uint4*)(rdn + cell);
    uint4 rq4 = *(const uint4*)(rq2 + cell);
    float exA[8], exmA[8], eyA[8], eymA[8], ezA[9], rdA[8], rqA[8];
    up8(ec, exA); up8(em, exmA); up8(yc, eyA); up8(ym4, eymA);
    ezA[0] = bf2f(ezm0); up8(zc, ezA + 1);
    up8(rd4, rdA); up8(rq4, rqA);
#pragma unroll
    for (int i = 0; i < 8; ++i) {
      float num = exA[i] * xpA[i];
      num = fmaf(exmA[i], xmA[i], num);
      num = fmaf(eyA[i],  ypA[i], num);
      num = fmaf(eymA[i], ymA[i], num);
      num = fmaf(ezA[i + 1], pz[i + 2], num);
      num = fmaf(ezA[i],     pz[i],     num);
      o[i] = fmaf(rdA[i], num, rqA[i]);
    }
  }
  *(float4*)(poutf + cell)     = make_float4(o[0], o[1], o[2], o[3]);
  *(float4*)(poutf + cell + 4) = make_float4(o[4], o[5], o[6], o[7]);
}

// ---------------------------------------------------------------------------
// Fallback fp32 Jacobi (tiny ws)
// ---------------------------------------------------------------------------
__global__ __launch_bounds__(256) void jacobi_kernel(
    const float* __restrict__ phi_in, float* __restrict__ phi_out,
    const float* __restrict__ eps, const float* __restrict__ rhs, int B) {
  int i = blockIdx.x * blockDim.x + threadIdx.x;
  if (i >= B * MCELLS) return;
  int b = i >> 21;
  int v = i & (MCELLS - 1);
  int z = v & 127, y = (v >> 7) & 127, x = v >> 14;

  const float* ex = eps + (size_t)(b * 4 + 0) * MCELLS;
  const float* ey = eps + (size_t)(b * 4 + 1) * MCELLS;
  const float* ez = eps + (size_t)(b * 4 + 2) * MCELLS;
  const float* lm = eps + (size_t)(b * 4 + 3) * MCELLS;
  const float* p  = phi_in + (size_t)b * MCELLS;

  float exc = ex[v], eyc = ey[v], ezc = ez[v];
  float exm = (x > 0) ? ex[v - BOX * BOX] : 0.0f;
  float eym = (y > 0) ? ey[v - BOX]       : 0.0f;
  float ezm = (z > 0) ? ez[v - 1]         : 0.0f;

  float num = rhs[i];
  num += (x < BOX - 1) ? exc * p[v + BOX * BOX] : 0.0f;
  num += (x > 0)       ? exm * p[v - BOX * BOX] : 0.0f;
  num += (y < BOX - 1) ? eyc * p[v + BOX]       : 0.0f;
  num += (y > 0)       ? eym * p[v - BOX]       : 0.0f;
  num += (z < BOX - 1) ? ezc * p[v + 1]         : 0.0f;
  num += (z > 0)       ? ezm * p[v - 1]         : 0.0f;

  float den = exc + exm + eyc + eym + ezc + ezm + 0.106f * lm[v];
  phi_out[i] = num / den;
}

// ---------------------------------------------------------------------------
extern "C" void kernel_launch(void* const* d_in, const int* in_sizes, int n_in,
                              void* d_out, int out_size, void* d_ws,
                              size_t ws_size, hipStream_t stream) {
  const float* coords    = (const float*)d_in[0];
  const float* params    = (const float*)d_in[1];
  const int*   num_atoms = (const int*)d_in[2];

  const int B = in_sizes[2];
  const int N = in_sizes[1] / (2 * B);

  float* out = (float*)d_out;
  float* q   = out;                            // (B, M)
  float* eps = out + (size_t)B * MCELLS;       // (B, 4, M)
  float* phi = out + (size_t)B * MCELLS * 5;   // (B, M)

  const size_t BM = (size_t)B * MCELLS;
  u16* phiA = (u16*)d_ws;
  u16* phiB = phiA + BM;
  u16* exb  = phiB + BM;
  u16* eyb  = exb + BM;
  u16* ezb  = eyb + BM;
  u16* rdn  = ezb + BM;
  u16* rq2  = rdn + BM;
  u16* pure16 = rq2 + BM;                       // (B, 128,128) u16 masks
  unsigned char* flags = (unsigned char*)(pure16 + (size_t)B * 16384);
  u16* zb = (u16*)(flags + (size_t)B * 4096);   // 64 B zero scratch
  const size_t need = BM * 14 + (size_t)B * (32768 + 4096) + 64;

  const bool fast = (ws_size >= need);

  hipMemsetAsync(q, 0, sizeof(float) * BM, stream);   // scatter accumulator

  eps_gather_kernel<<<dim3(16, 16, 16 * B), 256, 0, stream>>>(
      coords, params, num_atoms, eps, N);
  q_scatter_kernel<<<(B * N + 255) / 256, 256, 0, stream>>>(
      coords, params, num_atoms, q, N, B);

  if (fast) {
    const int pblocks = B * 1024;
    prep8_kernel<<<pblocks, 256, 0, stream>>>(eps, q, exb, eyb, ezb, rdn, rq2,
                                              phiA, pure16, B);
    flag_kernel<<<(B * 4096 + 255) / 256, 256, 0, stream>>>(pure16, flags, B);
    hipMemsetAsync(zb, 0, 64, stream);

    // prep did sweep 1 (phi1 in phiA). 14 fused pairs = sweeps 2..29,
    // ping-pong A->B->A (phi29 ends in A). Final single sweep 30 -> fp32 out.
    u16* pa = phiA;
    u16* pb = phiB;
    for (int k = 0; k < 14; ++k) {
      fused2_kernel<<<512 * B, 256, 0, stream>>>(
          pa, pb, exb, eyb, ezb, rdn, rq2, pure16, zb);
      u16* tmp = pa; pa = pb; pb = tmp;
    }
    const int units8 = B * (MCELLS / 8);
    sweep_final_kernel<<<(units8 + 255) / 256, 256, 0, stream>>>(
        pa, phi, exb, eyb, ezb, rdn, rq2, flags, units8);
  } else {
    hipMemsetAsync(phi, 0, sizeof(float) * BM, stream);
    float* pa = phi;
    float* pb = (float*)d_ws;
    int total = (int)BM;
    for (int it = 0; it < 30; ++it) {
      jacobi_kernel<<<(total + 255) / 256, 256, 0, stream>>>(pa, pb, eps, q, B);
      float* tmp = pa; pa = pb; pb = tmp;
    }
  }
}